// Round 14
// baseline (139.899 us; speedup 1.0000x reference)
//
#include <hip/hip_runtime.h>

constexpr int B = 4, H = 96, W = 96, HW = H * W;
constexpr int NPIX = B * HW;   // 36864
constexpr int KOFF = 18;       // 2*K offset channels

typedef _Float16 half8 __attribute__((ext_vector_type(8)));
typedef _Float16 half4 __attribute__((ext_vector_type(4)));
typedef float f32x4 __attribute__((ext_vector_type(4)));
typedef __attribute__((address_space(3))) _Float16 lf16;

__device__ __forceinline__ int iclamp(int v, int lo, int hi) {
  return v < lo ? lo : (v > hi ? hi : v);
}

struct Corners {
  int i00, i01, i10, i11;
  float w00, w01, w10, w11;
};

__device__ __forceinline__ Corners mk_corners(float py, float qx) {
  float fy = floorf(py), fx = floorf(qx);
  float wy = py - fy, wx = qx - fx;
  int y0 = (int)fy, x0 = (int)fx;
  int y1 = y0 + 1, x1 = x0 + 1;
  bool vy0 = (y0 >= 0) & (y0 < H);
  bool vy1 = (y1 >= 0) & (y1 < H);
  bool vx0 = (x0 >= 0) & (x0 < W);
  bool vx1 = (x1 >= 0) & (x1 < W);
  int r0 = iclamp(y0, 0, H - 1) * W;
  int r1 = iclamp(y1, 0, H - 1) * W;
  int c0 = iclamp(x0, 0, W - 1);
  int c1 = iclamp(x1, 0, W - 1);
  Corners cc;
  cc.i00 = r0 + c0; cc.i01 = r0 + c1; cc.i10 = r1 + c0; cc.i11 = r1 + c1;
  float a = 1.f - wy, bb = 1.f - wx;
  cc.w00 = a * bb * ((vy0 & vx0) ? 1.f : 0.f);
  cc.w01 = a * wx * ((vy0 & vx1) ? 1.f : 0.f);
  cc.w10 = wy * bb * ((vy1 & vx0) ? 1.f : 0.f);
  cc.w11 = wy * wx * ((vy1 & vx1) ? 1.f : 0.f);
  return cc;
}

// ---------- wave-local drain: stage + prefetch issued one tap ago are done ----------
__device__ __forceinline__ void vm_wait0() {
  asm volatile("s_waitcnt vmcnt(0)" ::: "memory");
  __builtin_amdgcn_sched_barrier(0);
}

// ---------- async global->LDS staging (AS3-typed; cast of named array folds) ----------
__device__ __forceinline__ void gld_lds16(const _Float16* g, lf16* l) {
  __builtin_amdgcn_global_load_lds(
      (const __attribute__((address_space(1))) void*)g,
      (__attribute__((address_space(3))) void*)l, 16, 0, 0);
}

// single-wave stage: frag f = 64 lanes x 16B contiguous -> linear LDS
template <int NF>
__device__ __forceinline__ void stage_frags(const _Float16* wk, lf16* lb, int lane) {
#pragma unroll
  for (int f = 0; f < NF; ++f)
    gld_lds16(wk + (size_t)f * 512 + lane * 8, lb + f * 512);
}

// ---------- fragment helpers ----------
template <int KS>
__device__ __forceinline__ void load_corners(const _Float16* xb, int ch, const Corners& cc,
                                             half8 r[KS][4]) {
  const _Float16* p00 = xb + (size_t)cc.i00 * (KS * 32) + ch;
  const _Float16* p01 = xb + (size_t)cc.i01 * (KS * 32) + ch;
  const _Float16* p10 = xb + (size_t)cc.i10 * (KS * 32) + ch;
  const _Float16* p11 = xb + (size_t)cc.i11 * (KS * 32) + ch;
#pragma unroll
  for (int ks = 0; ks < KS; ++ks) {
    r[ks][0] = *(const half8*)(p00 + ks * 32);
    r[ks][1] = *(const half8*)(p01 + ks * 32);
    r[ks][2] = *(const half8*)(p10 + ks * 32);
    r[ks][3] = *(const half8*)(p11 + ks * 32);
  }
}

template <int KS>
__device__ __forceinline__ void interp_corners(const Corners& cc, half8 r[KS][4],
                                               half8 a[KS]) {
  _Float16 q00 = (_Float16)cc.w00, q01 = (_Float16)cc.w01;
  _Float16 q10 = (_Float16)cc.w10, q11 = (_Float16)cc.w11;
#pragma unroll
  for (int ks = 0; ks < KS; ++ks)
    a[ks] = r[ks][0] * q00 + r[ks][1] * q01 + r[ks][2] * q10 + r[ks][3] * q11;
}

template <int KS>
__device__ __forceinline__ void load_shift(const _Float16* xb, int ch, int h, int w,
                                           int ky, int kx, half8 a[KS]) {
  int yy = h + ky, xx = w + kx;
  bool v = (yy >= 0) & (yy < H) & (xx >= 0) & (xx < W);
  int yc = iclamp(yy, 0, H - 1), xc = iclamp(xx, 0, W - 1);
  const _Float16* pv = xb + (size_t)(yc * W + xc) * (KS * 32) + ch;
#pragma unroll
  for (int ks = 0; ks < KS; ++ks) {
    half8 r = *(const half8*)(pv + ks * 32);
    half8 z = {0, 0, 0, 0, 0, 0, 0, 0};
    a[ks] = v ? r : z;
  }
}

// MFMA one tap, B-fragments from LDS (ds_read_b128; lane i reads bytes i*16 -> 2-way, free)
template <int KS, int NJ>
__device__ __forceinline__ void mfma_lds(const _Float16* lb, int lane,
                                         half8 a[KS], f32x4 acc[NJ]) {
#pragma unroll
  for (int ks = 0; ks < KS; ++ks)
#pragma unroll
    for (int j = 0; j < NJ; ++j) {
      half8 b = *(const half8*)(lb + (ks * NJ + j) * 512 + lane * 8);
      acc[j] = __builtin_amdgcn_mfma_f32_16x16x32_f16(a[ks], b, acc[j], 0, 0, 0);
    }
}

// ---------- fused weight prep: all 6 weight sets in one launch ----------
struct WAll {
  const float* src[6];
  _Float16* dst[6];
  int C[6], Osrc[6], OPAD[6], base[6];
};

__global__ void wfrag_all_kernel(WAll wa) {
  int bid = blockIdx.x;
  int s = 0;
#pragma unroll
  for (int i = 1; i < 6; ++i) s += (bid >= wa.base[i]) ? 1 : 0;
  int fid = bid - wa.base[s];
  int C = wa.C[s], Osrc = wa.Osrc[s], OPAD = wa.OPAD[s];
  const float* wsrc = wa.src[s];
  _Float16* wf = wa.dst[s];
  int KS = C / 32;
  int NJ = OPAD / 16;
  int lane = threadIdx.x;
  int j = fid % NJ;
  int ks = (fid / NJ) % KS;
  int k = fid / (NJ * KS);
  int o = j * 16 + (lane & 15);
  int c0 = ks * 32 + (lane >> 4) * 8;
  half8 v;
#pragma unroll
  for (int u = 0; u < 8; ++u)
    v[u] = (o < Osrc) ? (_Float16)wsrc[((size_t)o * C + c0 + u) * 9 + k] : (_Float16)0.f;
  *(half8*)(wf + ((size_t)fid * 64 + lane) * 8) = v;
}

// ---------- NCHW fp32 -> NHWC fp16 repack, both inputs in one launch (C=64) ----------
__global__ __launch_bounds__(256) void repack2_kernel(const float* __restrict__ in0,
                                                      const float* __restrict__ in1,
                                                      _Float16* __restrict__ o0,
                                                      _Float16* __restrict__ o1) {
  constexpr int C = 64;
  const float* in = blockIdx.y ? in1 : in0;
  _Float16* outh = blockIdx.y ? o1 : o0;
  __shared__ float tile[64 * C];
  int t = threadIdx.x;
  int pix0 = blockIdx.x * 64;
  int b = pix0 / HW;
  int hw0 = pix0 - b * HW;
  int l = t & 63;
  for (int cc = t >> 6; cc < C; cc += 4)
    tile[cc * 64 + l] = in[((size_t)b * C + cc) * HW + hw0 + l];
  __syncthreads();
  int pl = t >> 2;
  int cq = t & 3;
  _Float16* op = outh + (size_t)(pix0 + pl) * C + cq * (C / 4);
#pragma unroll
  for (int c = 0; c < C / 4; c += 4) {
    half4 hv;
#pragma unroll
    for (int u = 0; u < 4; ++u) hv[u] = (_Float16)tile[(cq * (C / 4) + c + u) * 64 + pl];
    *(half4*)(op + c) = hv;
  }
}

// ---------- fused stage: ONE wave (16 px), wave-private SINGLE-buffer LDS B,
// one vmcnt(0) per tap. Stage of tap k+1 issued AFTER tap-k's MFMA burst
// (ds_reads drained by the compiler's per-MFMA lgkmcnt waits -> WAR-safe);
// its latency is hidden by the second wave/SIMD that the halved LDS restores.
template <int C, int O, bool WF32, bool WH>
__global__ __launch_bounds__(64, 1)
void stage_kernel(const _Float16* __restrict__ xoff, const _Float16* __restrict__ xdef,
                  const _Float16* __restrict__ wfo, const float* __restrict__ bo,
                  const _Float16* __restrict__ wfd, const float* __restrict__ bd,
                  float* __restrict__ out, _Float16* __restrict__ outh) {
  constexpr int KS = C / 32;
  constexpr int NJ = O / 16;
  constexpr int NFD = KS * NJ;   // deform frags per tap
  constexpr int NFO = KS * 2;    // offset-conv frags per tap
  __shared__ _Float16 ldsB[NFD * 512];   // single buffer (19.6 KB total LDS)
  __shared__ float lofs[16][KOFF];
  lf16* lb3 = (lf16*)ldsB;
  const int lane = threadIdx.x;
  const int row = lane & 15;
  const int kgrp = lane >> 4;
  const int ch = kgrp * 8;
  // XCD-chunked swizzle: XCD (bid&7) gets a contiguous pixel range -> L2-resident
  const int chunk = (blockIdx.x & 7) * (int)(gridDim.x >> 3) + (blockIdx.x >> 3);
  const int px0 = chunk * 16;     // 16 | HW, wave never straddles batch
  const int b = px0 / HW;
  const int hw0 = px0 - b * HW;
  const int hwm = hw0 + row;
  const int h0 = hwm / W, w0 = hwm - h0 * W;
  const _Float16* xo = xoff + (size_t)b * HW * C;
  const _Float16* xd = xdef + (size_t)b * HW * C;

  // ---- phase 1: offset conv GEMM; B single-buffered in LDS ----
  {
    f32x4 aoc[2];
#pragma unroll
    for (int j = 0; j < 2; ++j) {
      int o = j * 16 + row;
      float bv = (o < KOFF) ? bo[o] : 0.f;
      aoc[j] = {bv, bv, bv, bv};
    }
    half8 a[KS], n[KS];
    stage_frags<NFO>(wfo, lb3, lane);                 // tap0 B
    load_shift<KS>(xo, ch, h0, w0, -1, -1, a);        // tap0 A
#pragma unroll
    for (int k = 0; k < 9; ++k) {
      vm_wait0();                                     // tap-k stage + A arrived
      if (k < 8) {
        int kn = k + 1;
        load_shift<KS>(xo, ch, h0, w0, kn / 3 - 1, kn % 3 - 1, n);  // covered by MFMA
      }
      mfma_lds<KS, 2>(ldsB, lane, a, aoc);
      if (k < 8) {
        stage_frags<NFO>(wfo + (size_t)(k + 1) * (NFO * 512), lb3, lane);  // WAR-safe
#pragma unroll
        for (int ks = 0; ks < KS; ++ks) a[ks] = n[ks];
      }
    }
    // offsets to pixel-major (same-wave LDS write->read; compiler orders via lgkmcnt)
#pragma unroll
    for (int j = 0; j < 2; ++j) {
      int o = j * 16 + row;
      if (o < KOFF) {
#pragma unroll
        for (int r = 0; r < 4; ++r) lofs[kgrp * 4 + r][o] = aoc[j][r];
      }
    }
  }

  // ---- phase 2: deformable conv GEMM; B single-buffer, corners prefetched 1 tap ----
  const float hf = (float)(h0 - 1), wwf = (float)(w0 - 1);

  f32x4 acc[NJ];
#pragma unroll
  for (int j = 0; j < NJ; ++j) {
    float bv = bd[j * 16 + row];
    acc[j] = {bv, bv, bv, bv};
  }
  half8 a[KS];
  half8 r[KS][4], rn[KS][4];
  Corners ccur = mk_corners(lofs[row][0] + hf, lofs[row][1] + wwf);
  stage_frags<NFD>(wfd, lb3, lane);     // tap0 B (after phase-1's last reads: WAR-safe)
  load_corners<KS>(xd, ch, ccur, r);
#pragma unroll
  for (int k = 0; k < 9; ++k) {
    vm_wait0();                         // tap-k stage + corners arrived
    interp_corners<KS>(ccur, r, a);     // r dead after this
    if (k < 8) {
      int kn = k + 1;
      Corners cn = mk_corners(lofs[row][2 * kn] + hf + (float)(kn / 3),
                              lofs[row][2 * kn + 1] + wwf + (float)(kn % 3));
      load_corners<KS>(xd, ch, cn, rn); // covered by the MFMA burst below
      ccur = cn;
    }
    mfma_lds<KS, NJ>(ldsB, lane, a, acc);
    if (k < 8) {
      stage_frags<NFD>(wfd + (size_t)(k + 1) * (NFD * 512), lb3, lane);  // WAR-safe
#pragma unroll
      for (int ks = 0; ks < KS; ++ks)
#pragma unroll
        for (int q = 0; q < 4; ++q) r[ks][q] = rn[ks][q];
    }
  }
  // ---- epilogue: D col(lane&15)=o, pixel = px0 + kgrp*4 + r ----
#pragma unroll
  for (int j = 0; j < NJ; ++j) {
    int o = j * 16 + row;
#pragma unroll
    for (int r2 = 0; r2 < 4; ++r2) {
      int p = px0 + kgrp * 4 + r2;
      if (WF32) out[((size_t)b * O + o) * HW + (p - b * HW)] = acc[j][r2];
      if (WH) outh[(size_t)p * O + o] = (_Float16)acc[j][r2];
    }
  }
}

extern "C" void kernel_launch(void* const* d_in, const int* in_sizes, int n_in,
                              void* d_out, int out_size, void* d_ws, size_t ws_size,
                              hipStream_t stream) {
  const float* x1  = (const float*)d_in[0];
  const float* y   = (const float*)d_in[1];
  const float* wo1 = (const float*)d_in[2];
  const float* bo1 = (const float*)d_in[3];
  const float* wd1 = (const float*)d_in[4];
  const float* bd1 = (const float*)d_in[5];
  const float* wo2 = (const float*)d_in[6];
  const float* bo2 = (const float*)d_in[7];
  const float* wd2 = (const float*)d_in[8];
  const float* bd2 = (const float*)d_in[9];
  const float* wo3 = (const float*)d_in[10];
  const float* bo3 = (const float*)d_in[11];
  const float* wd3 = (const float*)d_in[12];
  const float* bd3 = (const float*)d_in[13];
  float* out = (float*)d_out;

  char* p = (char*)d_ws;
  auto alloc = [&](size_t bytes) {
    char* r = p;
    p += (bytes + 255) & ~(size_t)255;
    return r;
  };
  _Float16* Wo1f = (_Float16*)alloc((size_t)9 * 2 * 2 * 512 * 2);   // 36 frags
  _Float16* Wo2f = (_Float16*)alloc((size_t)9 * 3 * 2 * 512 * 2);   // 54
  _Float16* Wo3f = (_Float16*)alloc((size_t)9 * 3 * 2 * 512 * 2);   // 54
  _Float16* W1f  = (_Float16*)alloc((size_t)9 * 2 * 6 * 512 * 2);   // 108
  _Float16* W2f  = (_Float16*)alloc((size_t)9 * 3 * 6 * 512 * 2);   // 162
  _Float16* W3f  = (_Float16*)alloc((size_t)9 * 3 * 4 * 512 * 2);   // 108
  _Float16* x1h = (_Float16*)alloc((size_t)NPIX * 64 * 2);
  _Float16* yh  = (_Float16*)alloc((size_t)NPIX * 64 * 2);
  _Float16* h1h = (_Float16*)alloc((size_t)NPIX * 96 * 2);
  _Float16* h2h = (_Float16*)alloc((size_t)NPIX * 96 * 2);

  // --- prep: one wfrag launch for all 6 weight sets ---
  WAll wa;
  wa.src[0] = wo1; wa.dst[0] = Wo1f; wa.C[0] = 64; wa.Osrc[0] = 18; wa.OPAD[0] = 32;
  wa.src[1] = wo2; wa.dst[1] = Wo2f; wa.C[1] = 96; wa.Osrc[1] = 18; wa.OPAD[1] = 32;
  wa.src[2] = wo3; wa.dst[2] = Wo3f; wa.C[2] = 96; wa.Osrc[2] = 18; wa.OPAD[2] = 32;
  wa.src[3] = wd1; wa.dst[3] = W1f;  wa.C[3] = 64; wa.Osrc[3] = 96; wa.OPAD[3] = 96;
  wa.src[4] = wd2; wa.dst[4] = W2f;  wa.C[4] = 96; wa.Osrc[4] = 96; wa.OPAD[4] = 96;
  wa.src[5] = wd3; wa.dst[5] = W3f;  wa.C[5] = 96; wa.Osrc[5] = 64; wa.OPAD[5] = 64;
  int base = 0;
  for (int i = 0; i < 6; ++i) {
    wa.base[i] = base;
    base += 9 * (wa.C[i] / 32) * (wa.OPAD[i] / 16);
  }
  hipLaunchKernelGGL(wfrag_all_kernel, dim3(base), dim3(64), 0, stream, wa);
  hipLaunchKernelGGL(repack2_kernel, dim3(NPIX / 64, 2), dim3(256), 0, stream,
                     x1, y, x1h, yh);

  dim3 gs(NPIX / 16);   // 2304 one-wave blocks (16 px each), XCD-chunked in-kernel
  dim3 wb(64);

  // stage 1: offsets from y; deform x1 -> h1h (C=64 -> O=96)
  hipLaunchKernelGGL((stage_kernel<64, 96, false, true>), gs, wb, 0, stream,
                     yh, x1h, Wo1f, bo1, W1f, bd1, (float*)nullptr, h1h);
  // stage 2: h1 -> h2h (C=96 -> O=96)
  hipLaunchKernelGGL((stage_kernel<96, 96, false, true>), gs, wb, 0, stream,
                     h1h, h1h, Wo2f, bo2, W2f, bd2, (float*)nullptr, h2h);
  // stage 3: h2 -> out (C=96 -> O=64)
  hipLaunchKernelGGL((stage_kernel<96, 64, true, false>), gs, wb, 0, stream,
                     h2h, h2h, Wo3f, bo3, W3f, bd3, out, (_Float16*)nullptr);
}

// Round 15
// 121.373 us; speedup vs baseline: 1.1526x; 1.1526x over previous
//
#include <hip/hip_runtime.h>

constexpr int B = 4, H = 96, W = 96, HW = H * W;
constexpr int NPIX = B * HW;   // 36864
constexpr int KOFF = 18;       // 2*K offset channels

typedef _Float16 half8 __attribute__((ext_vector_type(8)));
typedef _Float16 half4 __attribute__((ext_vector_type(4)));
typedef float f32x4 __attribute__((ext_vector_type(4)));
typedef __attribute__((address_space(3))) _Float16 lf16;

__device__ __forceinline__ int iclamp(int v, int lo, int hi) {
  return v < lo ? lo : (v > hi ? hi : v);
}

struct Corners {
  int i00, i01, i10, i11;
  float w00, w01, w10, w11;
};

__device__ __forceinline__ Corners mk_corners(float py, float qx) {
  float fy = floorf(py), fx = floorf(qx);
  float wy = py - fy, wx = qx - fx;
  int y0 = (int)fy, x0 = (int)fx;
  int y1 = y0 + 1, x1 = x0 + 1;
  bool vy0 = (y0 >= 0) & (y0 < H);
  bool vy1 = (y1 >= 0) & (y1 < H);
  bool vx0 = (x0 >= 0) & (x0 < W);
  bool vx1 = (x1 >= 0) & (x1 < W);
  int r0 = iclamp(y0, 0, H - 1) * W;
  int r1 = iclamp(y1, 0, H - 1) * W;
  int c0 = iclamp(x0, 0, W - 1);
  int c1 = iclamp(x1, 0, W - 1);
  Corners cc;
  cc.i00 = r0 + c0; cc.i01 = r0 + c1; cc.i10 = r1 + c0; cc.i11 = r1 + c1;
  float a = 1.f - wy, bb = 1.f - wx;
  cc.w00 = a * bb * ((vy0 & vx0) ? 1.f : 0.f);
  cc.w01 = a * wx * ((vy0 & vx1) ? 1.f : 0.f);
  cc.w10 = wy * bb * ((vy1 & vx0) ? 1.f : 0.f);
  cc.w11 = wy * wx * ((vy1 & vx1) ? 1.f : 0.f);
  return cc;
}

// ---------- async global->LDS staging (AS3-typed; cast of named array folds) ----------
__device__ __forceinline__ void gld_lds16(const _Float16* g, lf16* l) {
  __builtin_amdgcn_global_load_lds(
      (const __attribute__((address_space(1))) void*)g,
      (__attribute__((address_space(3))) void*)l, 16, 0, 0);
}

// 4-wave cooperative stage: frag f staged by wave (f & 3); 64 lanes x 16B per frag.
template <int NF>
__device__ __forceinline__ void stage_coop(const _Float16* wk, lf16* lb, int lane,
                                           int wid) {
#pragma unroll
  for (int i = 0; i < (NF + 3) / 4; ++i) {
    int f = i * 4 + wid;
    if (f < NF)   // wave-uniform predicate
      gld_lds16(wk + (size_t)f * 512 + lane * 8, lb + f * 512);
  }
}

// ---------- fragment helpers ----------
template <int KS>
__device__ __forceinline__ void load_corners(const _Float16* xb, int ch, const Corners& cc,
                                             half8 r[KS][4]) {
  const _Float16* p00 = xb + (size_t)cc.i00 * (KS * 32) + ch;
  const _Float16* p01 = xb + (size_t)cc.i01 * (KS * 32) + ch;
  const _Float16* p10 = xb + (size_t)cc.i10 * (KS * 32) + ch;
  const _Float16* p11 = xb + (size_t)cc.i11 * (KS * 32) + ch;
#pragma unroll
  for (int ks = 0; ks < KS; ++ks) {
    r[ks][0] = *(const half8*)(p00 + ks * 32);
    r[ks][1] = *(const half8*)(p01 + ks * 32);
    r[ks][2] = *(const half8*)(p10 + ks * 32);
    r[ks][3] = *(const half8*)(p11 + ks * 32);
  }
}

template <int KS>
__device__ __forceinline__ void interp_corners(const Corners& cc, half8 r[KS][4],
                                               half8 a[KS]) {
  _Float16 q00 = (_Float16)cc.w00, q01 = (_Float16)cc.w01;
  _Float16 q10 = (_Float16)cc.w10, q11 = (_Float16)cc.w11;
#pragma unroll
  for (int ks = 0; ks < KS; ++ks)
    a[ks] = r[ks][0] * q00 + r[ks][1] * q01 + r[ks][2] * q10 + r[ks][3] * q11;
}

template <int KS>
__device__ __forceinline__ void load_shift(const _Float16* xb, int ch, int h, int w,
                                           int ky, int kx, half8 a[KS]) {
  int yy = h + ky, xx = w + kx;
  bool v = (yy >= 0) & (yy < H) & (xx >= 0) & (xx < W);
  int yc = iclamp(yy, 0, H - 1), xc = iclamp(xx, 0, W - 1);
  const _Float16* pv = xb + (size_t)(yc * W + xc) * (KS * 32) + ch;
#pragma unroll
  for (int ks = 0; ks < KS; ++ks) {
    half8 r = *(const half8*)(pv + ks * 32);
    half8 z = {0, 0, 0, 0, 0, 0, 0, 0};
    a[ks] = v ? r : z;
  }
}

// MFMA one tap, B-fragments from LDS (ds_read_b128; lane i reads bytes i*16 -> 2-way, free)
template <int KS, int NJ>
__device__ __forceinline__ void mfma_lds(const _Float16* lb, int lane,
                                         half8 a[KS], f32x4 acc[NJ]) {
#pragma unroll
  for (int ks = 0; ks < KS; ++ks)
#pragma unroll
    for (int j = 0; j < NJ; ++j) {
      half8 b = *(const half8*)(lb + (ks * NJ + j) * 512 + lane * 8);
      acc[j] = __builtin_amdgcn_mfma_f32_16x16x32_f16(a[ks], b, acc[j], 0, 0, 0);
    }
}

// ---------- fused weight prep: all 6 weight sets in one launch ----------
struct WAll {
  const float* src[6];
  _Float16* dst[6];
  int C[6], Osrc[6], OPAD[6], base[6];
};

__global__ void wfrag_all_kernel(WAll wa) {
  int bid = blockIdx.x;
  int s = 0;
#pragma unroll
  for (int i = 1; i < 6; ++i) s += (bid >= wa.base[i]) ? 1 : 0;
  int fid = bid - wa.base[s];
  int C = wa.C[s], Osrc = wa.Osrc[s], OPAD = wa.OPAD[s];
  const float* wsrc = wa.src[s];
  _Float16* wf = wa.dst[s];
  int KS = C / 32;
  int NJ = OPAD / 16;
  int lane = threadIdx.x;
  int j = fid % NJ;
  int ks = (fid / NJ) % KS;
  int k = fid / (NJ * KS);
  int o = j * 16 + (lane & 15);
  int c0 = ks * 32 + (lane >> 4) * 8;
  half8 v;
#pragma unroll
  for (int u = 0; u < 8; ++u)
    v[u] = (o < Osrc) ? (_Float16)wsrc[((size_t)o * C + c0 + u) * 9 + k] : (_Float16)0.f;
  *(half8*)(wf + ((size_t)fid * 64 + lane) * 8) = v;
}

// ---------- NCHW fp32 -> NHWC fp16 repack, both inputs in one launch (C=64) ----------
__global__ __launch_bounds__(256) void repack2_kernel(const float* __restrict__ in0,
                                                      const float* __restrict__ in1,
                                                      _Float16* __restrict__ o0,
                                                      _Float16* __restrict__ o1) {
  constexpr int C = 64;
  const float* in = blockIdx.y ? in1 : in0;
  _Float16* outh = blockIdx.y ? o1 : o0;
  __shared__ float tile[64 * C];
  int t = threadIdx.x;
  int pix0 = blockIdx.x * 64;
  int b = pix0 / HW;
  int hw0 = pix0 - b * HW;
  int l = t & 63;
  for (int cc = t >> 6; cc < C; cc += 4)
    tile[cc * 64 + l] = in[((size_t)b * C + cc) * HW + hw0 + l];
  __syncthreads();
  int pl = t >> 2;
  int cq = t & 3;
  _Float16* op = outh + (size_t)(pix0 + pl) * C + cq * (C / 4);
#pragma unroll
  for (int c = 0; c < C / 4; c += 4) {
    half4 hv;
#pragma unroll
    for (int u = 0; u < 4; ++u) hv[u] = (_Float16)tile[(cq * (C / 4) + c + u) * 64 + pl];
    *(half4*)(op + c) = hv;
  }
}

// ---------- fused stage: 4 waves/block (64 px), B staged ONCE per block per tap
// (cooperative global_load_lds), double-buffered LDS, ONE barrier per tap (m97
// alternation: stage k+1 into the other buffer right after the barrier that ends
// tap-k-1's reads). Weight L2 traffic /4 vs the 1-wave versions.
template <int C, int O, bool WF32, bool WH>
__global__ __launch_bounds__(256, 1)
void stage_kernel(const _Float16* __restrict__ xoff, const _Float16* __restrict__ xdef,
                  const _Float16* __restrict__ wfo, const float* __restrict__ bo,
                  const _Float16* __restrict__ wfd, const float* __restrict__ bd,
                  float* __restrict__ out, _Float16* __restrict__ outh) {
  constexpr int KS = C / 32;
  constexpr int NJ = O / 16;
  constexpr int NFD = KS * NJ;   // deform frags per tap
  constexpr int NFO = KS * 2;    // offset-conv frags per tap
  __shared__ _Float16 ldsB[2 * NFD * 512];   // double buffer, shared by 4 waves
  __shared__ float lofs[64][KOFF];
  lf16* lb3 = (lf16*)ldsB;
  const int tid = threadIdx.x;
  const int wid = tid >> 6;
  const int lane = tid & 63;
  const int row = lane & 15;
  const int kgrp = lane >> 4;
  const int ch = kgrp * 8;
  // XCD-chunked swizzle (576 % 8 == 0 -> bijective)
  const int chunk = (blockIdx.x & 7) * (int)(gridDim.x >> 3) + (blockIdx.x >> 3);
  const int px0 = chunk * 64 + wid * 16;   // 64 | HW: block never straddles batch
  const int b = px0 / HW;
  const int hw0 = px0 - b * HW;
  const int hwm = hw0 + row;
  const int h0 = hwm / W, w0 = hwm - h0 * W;
  const _Float16* xo = xoff + (size_t)b * HW * C;
  const _Float16* xd = xdef + (size_t)b * HW * C;

  // ---- phase 1: offset conv GEMM; B staged cooperatively, dbuf, 1 barrier/tap ----
  {
    f32x4 aoc[2];
#pragma unroll
    for (int j = 0; j < 2; ++j) {
      int o = j * 16 + row;
      float bv = (o < KOFF) ? bo[o] : 0.f;
      aoc[j] = {bv, bv, bv, bv};
    }
    half8 a[KS], n[KS];
    stage_coop<NFO>(wfo, lb3, lane, wid);             // tap0 -> buf0
    load_shift<KS>(xo, ch, h0, w0, -1, -1, a);        // tap0 A
#pragma unroll
    for (int k = 0; k < 9; ++k) {
      __syncthreads();   // stage(k) done (vmcnt drained); buf[k^1] reads (k-1) done
      if (k < 8) {
        int kn = k + 1;
        stage_coop<NFO>(wfo + (size_t)kn * (NFO * 512),
                        lb3 + (kn & 1) * NFD * 512, lane, wid);
        load_shift<KS>(xo, ch, h0, w0, kn / 3 - 1, kn % 3 - 1, n);
      }
      mfma_lds<KS, 2>(ldsB + (k & 1) * NFD * 512, lane, a, aoc);
      if (k < 8) {
#pragma unroll
        for (int ks = 0; ks < KS; ++ks) a[ks] = n[ks];
      }
    }
    // offsets to pixel-major (own wave's 16 rows; same-wave write->read)
#pragma unroll
    for (int j = 0; j < 2; ++j) {
      int o = j * 16 + row;
      if (o < KOFF) {
#pragma unroll
        for (int r = 0; r < 4; ++r) lofs[wid * 16 + kgrp * 4 + r][o] = aoc[j][r];
      }
    }
  }
  __syncthreads();   // phase-1 buf0 reads done before phase-2 stages into buf0

  // ---- phase 2: deformable conv GEMM; same dbuf protocol, corners 1 tap ahead ----
  const int prow = wid * 16 + row;
  const float hf = (float)(h0 - 1), wwf = (float)(w0 - 1);

  f32x4 acc[NJ];
#pragma unroll
  for (int j = 0; j < NJ; ++j) {
    float bv = bd[j * 16 + row];
    acc[j] = {bv, bv, bv, bv};
  }
  half8 a[KS];
  half8 r[KS][4], rn[KS][4];
  Corners ccur = mk_corners(lofs[prow][0] + hf, lofs[prow][1] + wwf);
  stage_coop<NFD>(wfd, lb3, lane, wid);   // tap0 -> buf0
  load_corners<KS>(xd, ch, ccur, r);
#pragma unroll
  for (int k = 0; k < 9; ++k) {
    __syncthreads();   // stage(k) done; buf[k^1] reads (k-1) done
    if (k < 8) {
      int kn = k + 1;
      stage_coop<NFD>(wfd + (size_t)kn * (NFD * 512),
                      lb3 + (kn & 1) * NFD * 512, lane, wid);
      Corners cn = mk_corners(lofs[prow][2 * kn] + hf + (float)(kn / 3),
                              lofs[prow][2 * kn + 1] + wwf + (float)(kn % 3));
      load_corners<KS>(xd, ch, cn, rn);
      interp_corners<KS>(ccur, r, a);
      mfma_lds<KS, NJ>(ldsB + (k & 1) * NFD * 512, lane, a, acc);
      ccur = cn;
#pragma unroll
      for (int ks = 0; ks < KS; ++ks)
#pragma unroll
        for (int q = 0; q < 4; ++q) r[ks][q] = rn[ks][q];
    } else {
      interp_corners<KS>(ccur, r, a);
      mfma_lds<KS, NJ>(ldsB + (k & 1) * NFD * 512, lane, a, acc);
    }
  }
  // ---- epilogue: D col(lane&15)=o, pixel = px0 + kgrp*4 + r ----
#pragma unroll
  for (int j = 0; j < NJ; ++j) {
    int o = j * 16 + row;
#pragma unroll
    for (int r2 = 0; r2 < 4; ++r2) {
      int p = px0 + kgrp * 4 + r2;
      if (WF32) out[((size_t)b * O + o) * HW + (p - b * HW)] = acc[j][r2];
      if (WH) outh[(size_t)p * O + o] = (_Float16)acc[j][r2];
    }
  }
}

extern "C" void kernel_launch(void* const* d_in, const int* in_sizes, int n_in,
                              void* d_out, int out_size, void* d_ws, size_t ws_size,
                              hipStream_t stream) {
  const float* x1  = (const float*)d_in[0];
  const float* y   = (const float*)d_in[1];
  const float* wo1 = (const float*)d_in[2];
  const float* bo1 = (const float*)d_in[3];
  const float* wd1 = (const float*)d_in[4];
  const float* bd1 = (const float*)d_in[5];
  const float* wo2 = (const float*)d_in[6];
  const float* bo2 = (const float*)d_in[7];
  const float* wd2 = (const float*)d_in[8];
  const float* bd2 = (const float*)d_in[9];
  const float* wo3 = (const float*)d_in[10];
  const float* bo3 = (const float*)d_in[11];
  const float* wd3 = (const float*)d_in[12];
  const float* bd3 = (const float*)d_in[13];
  float* out = (float*)d_out;

  char* p = (char*)d_ws;
  auto alloc = [&](size_t bytes) {
    char* r = p;
    p += (bytes + 255) & ~(size_t)255;
    return r;
  };
  _Float16* Wo1f = (_Float16*)alloc((size_t)9 * 2 * 2 * 512 * 2);   // 36 frags
  _Float16* Wo2f = (_Float16*)alloc((size_t)9 * 3 * 2 * 512 * 2);   // 54
  _Float16* Wo3f = (_Float16*)alloc((size_t)9 * 3 * 2 * 512 * 2);   // 54
  _Float16* W1f  = (_Float16*)alloc((size_t)9 * 2 * 6 * 512 * 2);   // 108
  _Float16* W2f  = (_Float16*)alloc((size_t)9 * 3 * 6 * 512 * 2);   // 162
  _Float16* W3f  = (_Float16*)alloc((size_t)9 * 3 * 4 * 512 * 2);   // 108
  _Float16* x1h = (_Float16*)alloc((size_t)NPIX * 64 * 2);
  _Float16* yh  = (_Float16*)alloc((size_t)NPIX * 64 * 2);
  _Float16* h1h = (_Float16*)alloc((size_t)NPIX * 96 * 2);
  _Float16* h2h = (_Float16*)alloc((size_t)NPIX * 96 * 2);

  // --- prep: one wfrag launch for all 6 weight sets ---
  WAll wa;
  wa.src[0] = wo1; wa.dst[0] = Wo1f; wa.C[0] = 64; wa.Osrc[0] = 18; wa.OPAD[0] = 32;
  wa.src[1] = wo2; wa.dst[1] = Wo2f; wa.C[1] = 96; wa.Osrc[1] = 18; wa.OPAD[1] = 32;
  wa.src[2] = wo3; wa.dst[2] = Wo3f; wa.C[2] = 96; wa.Osrc[2] = 18; wa.OPAD[2] = 32;
  wa.src[3] = wd1; wa.dst[3] = W1f;  wa.C[3] = 64; wa.Osrc[3] = 96; wa.OPAD[3] = 96;
  wa.src[4] = wd2; wa.dst[4] = W2f;  wa.C[4] = 96; wa.Osrc[4] = 96; wa.OPAD[4] = 96;
  wa.src[5] = wd3; wa.dst[5] = W3f;  wa.C[5] = 96; wa.Osrc[5] = 64; wa.OPAD[5] = 64;
  int base = 0;
  for (int i = 0; i < 6; ++i) {
    wa.base[i] = base;
    base += 9 * (wa.C[i] / 32) * (wa.OPAD[i] / 16);
  }
  hipLaunchKernelGGL(wfrag_all_kernel, dim3(base), dim3(64), 0, stream, wa);
  hipLaunchKernelGGL(repack2_kernel, dim3(NPIX / 64, 2), dim3(256), 0, stream,
                     x1, y, x1h, yh);

  dim3 gs(NPIX / 64);   // 576 four-wave blocks (64 px each), XCD-chunked in-kernel
  dim3 wb(256);

  // stage 1: offsets from y; deform x1 -> h1h (C=64 -> O=96)
  hipLaunchKernelGGL((stage_kernel<64, 96, false, true>), gs, wb, 0, stream,
                     yh, x1h, Wo1f, bo1, W1f, bd1, (float*)nullptr, h1h);
  // stage 2: h1 -> h2h (C=96 -> O=96)
  hipLaunchKernelGGL((stage_kernel<96, 96, false, true>), gs, wb, 0, stream,
                     h1h, h1h, Wo2f, bo2, W2f, bd2, (float*)nullptr, h2h);
  // stage 3: h2 -> out (C=96 -> O=64)
  hipLaunchKernelGGL((stage_kernel<96, 64, true, false>), gs, wb, 0, stream,
                     h2h, h2h, Wo3f, bo3, W3f, bd3, out, (_Float16*)nullptr);
}